// Round 9
// baseline (578.981 us; speedup 1.0000x reference)
//
#include <hip/hip_runtime.h>
#include <hip/hip_bf16.h>
#include <math.h>

// Problem constants
#define Tn 2048
#define Dn 3584
#define NH 28
#define KHn 4
#define Hn 128
#define Gn 7            // NH / KHn
#define SCALE 0.08838834764831845f  // 1/sqrt(128)
#define LDC 4608        // combined qkv row stride (q:0..3583, k:3584..4095, v:4096..4607)
#define KOFF 3584
#define VOFF 4096
// flash tiles (block = 128 q-rows, wave owns 2x16 strips)
#define FBQ 128
#define FBS 64
#define MAXT 8          // max KV tiles per block (work-balanced chunks)
// fixed softmax shift: S*scale has std~1.4, |max|~8 << shift; exp(S-12) is
// exactly softmax up to fp rounding (scale cancels in the final divide).
// Also makes split partials ADDITIVE (no max merge) -> free-form chunking.
#define EXP_SHIFT 12.0f

typedef unsigned short u16;
typedef __attribute__((ext_vector_type(8))) short short8;   // 8 bf16 (4 VGPRs)
typedef __attribute__((ext_vector_type(4))) float floatx4;  // MFMA acc

// Work-balanced (qt, s) chunk table: q-tile qt has nst=2qt+2 KV tiles, cut
// into ceil(nst/8) chunks of <=8 tiles. 28 full-8 chunks first (heavy),
// then 12 small gap-fillers. Sum of sizes = 272 tile-units per head.
__device__ __constant__ unsigned char QT_TAB[40] = {
    15,15,15,15, 14,14,14, 13,13,13, 12,12,12, 11,11,11,
    10,10, 9,9, 8,8, 7,7, 6, 5, 4, 3,
    14,10,6,2, 13,9,5,1, 12,8,4,0};
__device__ __constant__ unsigned char S_TAB[40] = {
     0, 1, 2, 3,  0, 1, 2,  0, 1, 2,  0, 1, 2,  0, 1, 2,
     0, 1, 0,1, 0,1, 0,1, 0, 0, 0, 0,
     3, 2,1,0,  3,2,1,0,  3,2,1,0};

// ---------------- bf16 helpers ----------------
__device__ __forceinline__ float bf_lo(unsigned int u) {
    union { unsigned int i; float f; } x; x.i = u << 16; return x.f;
}
__device__ __forceinline__ u16 f2bf(float f) {
    __hip_bfloat16 h = __float2bfloat16(f);
    return *reinterpret_cast<u16*>(&h);
}

// ---------------------------------------------------------------------------
// x fp32 -> bf16 cast (vectorized)
// ---------------------------------------------------------------------------
__global__ void cast_f32_bf16(const float* __restrict__ in, u16* __restrict__ out, int n4)
{
    const int idx = blockIdx.x * blockDim.x + threadIdx.x;
    if (idx >= n4) return;
    const float4 f = ((const float4*)in)[idx];
    ((ushort4*)out)[idx] = make_ushort4(f2bf(f.x), f2bf(f.y), f2bf(f.z), f2bf(f.w));
}

// ---------------------------------------------------------------------------
// zero fp32 buffer (for per-split l accumulators)
// NOTE: lbf aliases the (dead-after-QKV-GEMM) wv^T tail of wt — this kernel
// MUST be launched after the QKV GEMM (round-6 bug: launching it before the
// GEMM zeroed live wv^T weights -> absmax 2.68).
// ---------------------------------------------------------------------------
__global__ void zero_f32(float* __restrict__ p, int n)
{
    const int i = blockIdx.x * blockDim.x + threadIdx.x;
    if (i < n) p[i] = 0.f;
}

// ---------------------------------------------------------------------------
// Transpose + cast: out[c][r] = bf16(in[r][c]); in (R x C) fp32, out stride ldo.
// ---------------------------------------------------------------------------
__global__ __launch_bounds__(256) void transpose_cast(
    const float* __restrict__ in, u16* __restrict__ out, int R, int C, int ldo)
{
    __shared__ float ts[32][33];
    const int tid = threadIdx.x;
    const int c0 = blockIdx.x * 32, r0 = blockIdx.y * 32;
    const int tx = tid & 31, ty = tid >> 5;  // ty 0..7
    #pragma unroll
    for (int i = 0; i < 4; ++i)
        ts[ty + i * 8][tx] = in[(size_t)(r0 + ty + i * 8) * C + c0 + tx];
    __syncthreads();
    #pragma unroll
    for (int i = 0; i < 4; ++i)
        out[(size_t)(c0 + ty + i * 8) * ldo + r0 + tx] = f2bf(ts[tx][ty + i * 8]);
}

// ---------------------------------------------------------------------------
// Transpose V out of combined qkv: vt[D][s] = qkv[s][VOFF + D], D in [0,512)
// ---------------------------------------------------------------------------
__global__ __launch_bounds__(256) void transpose_v(
    const u16* __restrict__ qkv, u16* __restrict__ vt)
{
    __shared__ u16 ts[32][33];
    const int tid = threadIdx.x;
    const int s0 = blockIdx.x * 32, d0 = blockIdx.y * 32;
    const int tx = tid & 31, ty = tid >> 5;
    #pragma unroll
    for (int i = 0; i < 4; ++i)
        ts[ty + i * 8][tx] = qkv[(size_t)(s0 + ty + i * 8) * LDC + VOFF + d0 + tx];
    __syncthreads();
    #pragma unroll
    for (int i = 0; i < 4; ++i)
        vt[(size_t)(d0 + ty + i * 8) * Tn + s0 + tx] = ts[tx][ty + i * 8];
}

// ---------------------------------------------------------------------------
// Concat bias: [q_bias | k_bias | v_bias] -> 4608
// ---------------------------------------------------------------------------
__global__ void concat_bias(const float* __restrict__ qb, const float* __restrict__ kb,
                            const float* __restrict__ vb, float* __restrict__ out)
{
    const int j = blockIdx.x * blockDim.x + threadIdx.x;
    if (j >= 4608) return;
    out[j] = j < 3584 ? qb[j] : (j < 4096 ? kb[j - 3584] : vb[j - 4096]);
}

// ---------------------------------------------------------------------------
// bf16 MFMA GEMM (m97 structure): C[M x N] = A[M x K] * Bt[N x K]^T (+bias)
// + XCD-aware bijective blockIdx swizzle (grids 576/448 are 8-divisible).
// ---------------------------------------------------------------------------
#define GM 128
#define GN 128
#define GK 32

__device__ __forceinline__ void async16(const void* g, void* l) {
    __builtin_amdgcn_global_load_lds(
        (const __attribute__((address_space(1))) unsigned int*)g,
        (__attribute__((address_space(3))) unsigned int*)l, 16, 0, 0);
}

template <typename OUT_T>
__global__ __launch_bounds__(256) void gemm_bf16_mfma(
    const u16* __restrict__ A, const u16* __restrict__ Bt,
    const float* __restrict__ bias, OUT_T* __restrict__ C,
    int M, int N, int K, int ldc)
{
    __shared__ __align__(16) u16 As[GM * GK];   // 8 KB
    __shared__ __align__(16) u16 Bs[GN * GK];   // 8 KB

    const int tid  = threadIdx.x;
    const int lane = tid & 63;
    const int wave = tid >> 6;
    const int wr = wave >> 1, wc = wave & 1;
    const int m16 = lane & 15, quad = lane >> 4;

    // XCD-aware swizzle: 8 XCDs get contiguous block ranges (L2 locality).
    const int nwg = gridDim.x * gridDim.y;      // divisible by 8 for our shapes
    const int bid = blockIdx.y * gridDim.x + blockIdx.x;
    const int cpx = nwg >> 3;
    const int swz = (bid & 7) * cpx + (bid >> 3);
    const int bm = (swz / gridDim.x) * GM;
    const int bn = (swz % gridDim.x) * GN;

    floatx4 acc[4][4];
    #pragma unroll
    for (int i = 0; i < 4; ++i)
        #pragma unroll
        for (int j = 0; j < 4; ++j) acc[i][j] = (floatx4)0.f;

    const int rl   = lane >> 2;
    const int kcol = (lane & 3) * 8;

    for (int k0 = 0; k0 < K; k0 += GK) {
        __syncthreads();
        #pragma unroll
        for (int i = 0; i < 2; ++i) {
            const int c = wave + i * 4;
            const int row = c * 16 + rl;
            async16(A  + (size_t)(bm + row) * K + k0 + kcol, &As[c * 512]);
            async16(Bt + (size_t)(bn + row) * K + k0 + kcol, &Bs[c * 512]);
        }
        __builtin_amdgcn_s_waitcnt(0);
        __syncthreads();

        short8 af[4], bfr[4];
        #pragma unroll
        for (int i = 0; i < 4; ++i)
            af[i] = *(const short8*)&As[(wr * 64 + i * 16 + m16) * GK + quad * 8];
        #pragma unroll
        for (int j = 0; j < 4; ++j)
            bfr[j] = *(const short8*)&Bs[(wc * 64 + j * 16 + m16) * GK + quad * 8];
        #pragma unroll
        for (int i = 0; i < 4; ++i)
            #pragma unroll
            for (int j = 0; j < 4; ++j)
                acc[i][j] = __builtin_amdgcn_mfma_f32_16x16x32_bf16(
                    af[i], bfr[j], acc[i][j], 0, 0, 0);
    }

    #pragma unroll
    for (int j = 0; j < 4; ++j) {
        const int col = bn + wc * 64 + j * 16 + m16;
        const float bv = bias ? bias[col] : 0.f;
        #pragma unroll
        for (int i = 0; i < 4; ++i) {
            const int rbase = bm + wr * 64 + i * 16 + quad * 4;
            #pragma unroll
            for (int r = 0; r < 4; ++r) {
                const float v = acc[i][j][r] + bv;
                if constexpr (sizeof(OUT_T) == 2)
                    C[(size_t)(rbase + r) * ldc + col] = (OUT_T)f2bf(v);
                else
                    C[(size_t)(rbase + r) * ldc + col] = v;
            }
        }
    }
}

// ---------------------------------------------------------------------------
// RoPE in place on bf16 strided buffer. heads=32 covers q (0..27) + k (28..31).
// ---------------------------------------------------------------------------
__global__ void rope_bf16(u16* __restrict__ base,
                          const float* __restrict__ sin_t,
                          const float* __restrict__ cos_t,
                          int heads)
{
    const int idx = blockIdx.x * blockDim.x + threadIdx.x;
    const int n_elem = Tn * heads * 64;
    if (idx >= n_elem) return;
    const int i = idx & 63;
    const int h = (idx >> 6) % heads;
    const int t = idx / (64 * heads);
    const float s = sin_t[t * 64 + i];
    const float c = cos_t[t * 64 + i];
    u16* p = base + (size_t)t * LDC + h * Hn;
    const float x1 = bf_lo((unsigned int)p[i]);
    const float x2 = bf_lo((unsigned int)p[i + 64]);
    p[i]      = f2bf(x1 * c - x2 * s);
    p[i + 64] = f2bf(x2 * c + x1 * s);
}

// ---------------------------------------------------------------------------
// MFMA flash attention, UNSTAGED + work-balanced:
// - K and V MFMA fragments read DIRECTLY from global (L2/L1-hot: all 4
//   waves of a block read the same 32KB tile -> fits L1; K+V per kv-head
//   = 1MB, shared by 7 q-heads -> L2-resident). Round-4 evidence: this
//   structure is the ONLY one with WRITE_SIZE == data (no inflation);
//   every LDS-staged variant wrote 4.5-6.5x phantom bytes (r0/3/5/7/8),
//   and r8 proved the O-store pattern is NOT the cause.
// - ZERO barriers, no prefetch registers; Ps (P=exp operand) in LDS only
//   (wave-private rows). LDS 18KB -> 4+ blocks/CU; VGPR ~130 -> 4 w/SIMD.
// - Work-balanced <=8-tile chunks (QT_TAB/S_TAB) fixed r4's tail problem;
//   fixed-shift softmax removed its shuffle chains. TLP now hides L2 lat.
// - Epilogue: O re-staged through dead Ps (wave-private, no barrier) so
//   partial-O stores are full 64B lines.
// ---------------------------------------------------------------------------
__global__ __launch_bounds__(256, 2) void flash_attn_mfma(
    const u16* __restrict__ qkv, const u16* __restrict__ vt,
    u16* __restrict__ pb01, u16* __restrict__ pb23,
    float* __restrict__ lb)
{
    const int qt = (int)QT_TAB[blockIdx.x];
    const int s  = (int)S_TAB[blockIdx.x];
    const int n  = blockIdx.y;
    const int kh = n / Gn;
    const int tid  = threadIdx.x;
    const int lane = tid & 63;
    const int w    = tid >> 6;
    const int m16  = lane & 15;
    const int quad = lane >> 4;

    __shared__ __align__(16) u16 Ps[128 * 72];   // 18432 B, wave-private rows

    // Q fragments (A-operand), rows w*32 + p*16 + m16, loaded once
    short8 qf[2][4];
    #pragma unroll
    for (int p = 0; p < 2; ++p) {
        const int qrow = qt * FBQ + w * 32 + p * 16 + m16;
        const u16* qp = qkv + (size_t)qrow * LDC + n * Hn;
        #pragma unroll
        for (int kc = 0; kc < 4; ++kc)
            qf[p][kc] = *(const short8*)(qp + kc * 32 + quad * 8);
    }

    floatx4 oacc[2][8];
    #pragma unroll
    for (int p = 0; p < 2; ++p)
        #pragma unroll
        for (int jn = 0; jn < 8; ++jn) oacc[p][jn] = (floatx4)0.f;
    float lrow[2][4];
    #pragma unroll
    for (int p = 0; p < 2; ++p)
        #pragma unroll
        for (int r = 0; r < 4; ++r) lrow[p][r] = 0.f;

    const int nst = 2 * qt + 2;
    const int st0 = s * MAXT;
    const int st1 = (st0 + MAXT < nst) ? st0 + MAXT : nst;

    // per-lane fragment base offsets (row-part from m16, col-part from quad)
    const u16* kfrag = qkv + (size_t)m16 * LDC + KOFF + kh * Hn + quad * 8;
    const u16* vfrag = vt + (size_t)(kh * Hn + m16) * Tn + quad * 8;

    for (int st = st0; st < st1; ++st) {
        // wave-uniform skip of fully-masked wave-tiles (no barriers: free)
        if ((st * FBS) > (qt * FBQ + w * 32 + 31)) continue;

        const u16* kb = kfrag + (size_t)(st * FBS) * LDC;
        const u16* vb = vfrag + st * FBS;

        // ---------------- QK^T (K frags direct from global/L2) ----------------
        floatx4 sacc[2][4];
        #pragma unroll
        for (int j = 0; j < 4; ++j) sacc[0][j] = (floatx4)0.f;
        #pragma unroll
        for (int j = 0; j < 4; ++j) sacc[1][j] = (floatx4)0.f;
        #pragma unroll
        for (int j = 0; j < 4; ++j) {
            #pragma unroll
            for (int kc = 0; kc < 4; ++kc) {
                const short8 bfv = *(const short8*)(kb + (size_t)(j * 16) * LDC + kc * 32);
                sacc[0][j] = __builtin_amdgcn_mfma_f32_16x16x32_bf16(qf[0][kc], bfv, sacc[0][j], 0, 0, 0);
                sacc[1][j] = __builtin_amdgcn_mfma_f32_16x16x32_bf16(qf[1][kc], bfv, sacc[1][j], 0, 0, 0);
            }
        }

        // ---- fixed-shift softmax: P = exp(S*scale - 12), no max chain ----
        const bool diag = (st >= 2 * qt);
        #pragma unroll
        for (int p = 0; p < 2; ++p) {
            #pragma unroll
            for (int r = 0; r < 4; ++r) {
                const int prow = w * 32 + p * 16 + quad * 4 + r;
                const int row  = qt * FBQ + prow;
                float ls = 0.f;
                #pragma unroll
                for (int j = 0; j < 4; ++j) {
                    float sv = sacc[p][j][r] * SCALE - EXP_SHIFT;
                    if (diag && (st * FBS + j * 16 + m16 > row)) sv = -1.0e30f;
                    const float e = __expf(sv);
                    ls += e;
                    Ps[prow * 72 + j * 16 + m16] = f2bf(e);
                }
                lrow[p][r] += ls;   // lane-partial, no rescale needed
            }
        }

        // ---------------- PV (V frags direct from global/L2) ----------------
        #pragma unroll
        for (int kc2 = 0; kc2 < 2; ++kc2) {
            const short8 af0 = *(const short8*)&Ps[(w * 32 + m16) * 72 + kc2 * 32 + quad * 8];
            const short8 af1 = *(const short8*)&Ps[(w * 32 + 16 + m16) * 72 + kc2 * 32 + quad * 8];
            #pragma unroll
            for (int jn = 0; jn < 8; ++jn) {
                const short8 bfv = *(const short8*)(vb + (size_t)(jn * 16) * Tn + kc2 * 32);
                oacc[0][jn] = __builtin_amdgcn_mfma_f32_16x16x32_bf16(af0, bfv, oacc[0][jn], 0, 0, 0);
                oacc[1][jn] = __builtin_amdgcn_mfma_f32_16x16x32_bf16(af1, bfv, oacc[1][jn], 0, 0, 0);
            }
        }
    }

    // ---- epilogue: butterfly-reduce l, local-normalize ----
    float lsum[2][4], invl[2][4];
    #pragma unroll
    for (int p = 0; p < 2; ++p)
        #pragma unroll
        for (int r = 0; r < 4; ++r) {
            float l = lrow[p][r];
            l += __shfl_xor(l, 1); l += __shfl_xor(l, 2);
            l += __shfl_xor(l, 4); l += __shfl_xor(l, 8);
            lsum[p][r] = l;
            invl[p][r] = (l > 0.f) ? 1.0f / l : 0.f;
        }

    if (m16 == 0) {
        #pragma unroll
        for (int p = 0; p < 2; ++p)
            #pragma unroll
            for (int r = 0; r < 4; ++r) {
                const int row = qt * FBQ + w * 32 + p * 16 + quad * 4 + r;
                lb[((size_t)s * NH + n) * Tn + row] = lsum[p][r];
            }
    }

    // ---- O store: re-stage through dead Ps (wave-private, no barrier) so
    // every 64B line of the partial buffer is written in full.
    u16* po = (s < 2) ? pb01 + (size_t)s * Tn * Dn
                      : pb23 + (size_t)(s - 2) * Tn * Dn;
    const int orow_l = w * 32 + (lane >> 1);       // this lane's readback row
    const int seg    = lane & 1;
    #pragma unroll
    for (int h = 0; h < 2; ++h) {                  // column halves 0-63, 64-127
        // stage: wave's 32 rows x 64 cols into Ps[row][0..63]
        #pragma unroll
        for (int p = 0; p < 2; ++p)
            #pragma unroll
            for (int r = 0; r < 4; ++r) {
                const int mrw = w * 32 + p * 16 + quad * 4 + r;
                #pragma unroll
                for (int j4 = 0; j4 < 4; ++j4)
                    Ps[mrw * 72 + j4 * 16 + m16] =
                        f2bf(oacc[p][h * 4 + j4][r] * invl[p][r]);
            }
        // readback: 2 lanes/row x 64B contiguous (full lines)
        u16* orow = po + (size_t)(qt * FBQ + orow_l) * Dn + n * Hn + h * 64 + seg * 32;
        #pragma unroll
        for (int i = 0; i < 4; ++i) {
            const uint4 d = *(const uint4*)&Ps[orow_l * 72 + seg * 32 + i * 8];
            *(uint4*)(orow + i * 8) = d;
        }
    }
}

// ---------------------------------------------------------------------------
// Combine up to 4 normalized bf16 partials: out = sum(l_i*o_i)/sum(l_i).
// Slots with l==0 (unused splits for this qt) are skipped.
// ---------------------------------------------------------------------------
__global__ __launch_bounds__(256) void combine_splits(
    const u16* __restrict__ pb01, const u16* __restrict__ pb23,
    const float* __restrict__ lb, u16* __restrict__ ob)
{
    const int idx = blockIdx.x * blockDim.x + threadIdx.x;
    const int n4  = Tn * Dn / 4;
    if (idx >= n4) return;
    const int c4  = idx % (Dn / 4);
    const int row = idx / (Dn / 4);
    const int n   = (c4 * 4) >> 7;   // /Hn

    float den = 0.f, ax = 0.f, ay = 0.f, az = 0.f, aw = 0.f;
    #pragma unroll
    for (int s = 0; s < 4; ++s) {
        const float l = lb[((size_t)s * NH + n) * Tn + row];
        if (l > 0.f) {
            const u16* p = (s < 2) ? pb01 + (size_t)s * Tn * Dn
                                   : pb23 + (size_t)(s - 2) * Tn * Dn;
            const ushort4 v = ((const ushort4*)p)[idx];
            den += l;
            ax += l * bf_lo((unsigned int)v.x);
            ay += l * bf_lo((unsigned int)v.y);
            az += l * bf_lo((unsigned int)v.z);
            aw += l * bf_lo((unsigned int)v.w);
        }
    }
    const float inv = 1.0f / den;   // s=0 always populated
    ushort4 o;
    o.x = f2bf(ax * inv);
    o.y = f2bf(ay * inv);
    o.z = f2bf(az * inv);
    o.w = f2bf(aw * inv);
    ((ushort4*)ob)[idx] = o;
}

// ---------------------------------------------------------------------------
// Launch
// ---------------------------------------------------------------------------
extern "C" void kernel_launch(void* const* d_in, const int* in_sizes, int n_in,
                              void* d_out, int out_size, void* d_ws, size_t ws_size,
                              hipStream_t stream)
{
    const float* x      = (const float*)d_in[0];
    const float* sin_t  = (const float*)d_in[2];
    const float* cos_t  = (const float*)d_in[3];
    const float* wq     = (const float*)d_in[4];
    const float* wk     = (const float*)d_in[5];
    const float* wv     = (const float*)d_in[6];
    const float* wo     = (const float*)d_in[7];
    const float* q_bias = (const float*)d_in[8];
    const float* k_bias = (const float*)d_in[9];
    const float* v_bias = (const float*)d_in[10];
    float* out = (float*)d_out;

    char* ws = (char*)d_ws;
    u16*  cqkv = (u16*)ws;                                  // 2048*4608 bf16 = 18,874,368
    u16*  abuf = (u16*)(ws + 18874368);                     // 2048*3584 bf16 = 14,680,064
    u16*  wt   = (u16*)(ws + 18874368 + 14680064);          // 4608*3584 bf16 (reused); @33,554,432
    float* bqkv = (float*)(ws + 66584576);                  // 4608 fp32
    u16*  vtg  = wt;                // V^T [512][2048] aliases wt head (2,097,152 B)
    // flash partials (live: flash -> combine only), bf16 normalized:
    // slots 0,1 -> d_out (xb dead); slots 2,3 -> dead wt region past vtg.
    u16*  pb01 = (u16*)d_out;                      // 2 x 14,680,064 = 29,360,128 (exact fit)
    u16*  pb23 = (u16*)(ws + 35651584);            // 2 x 14,680,064, ends 65,011,712
    float* lbf = (float*)(ws + 65011712);          // 4*28*2048*4 = 917,504, ends 65,929,216
    u16*  xb   = (u16*)d_out;   // x-bf16 scratch in d_out (dead before flash)

    // 1) casts / transposes / bias concat
    cast_f32_bf16<<<(Tn * Dn / 4 + 255) / 256, 256, 0, stream>>>(x, xb, Tn * Dn / 4);
    transpose_cast<<<dim3(Dn / 32, Dn / 32), 256, 0, stream>>>(wq, wt, Dn, Dn, Dn);
    transpose_cast<<<dim3(512 / 32, Dn / 32), 256, 0, stream>>>(wk, wt + (size_t)KOFF * Dn, Dn, 512, Dn);
    transpose_cast<<<dim3(512 / 32, Dn / 32), 256, 0, stream>>>(wv, wt + (size_t)VOFF * Dn, Dn, 512, Dn);
    concat_bias<<<18, 256, 0, stream>>>(q_bias, k_bias, v_bias, bqkv);

    // 2) fused QKV projection (bf16 MFMA)
    gemm_bf16_mfma<u16><<<dim3(LDC / GN, Tn / GM), 256, 0, stream>>>(
        xb, wt, bqkv, cqkv, Tn, LDC, Dn, LDC);

    // 2b) zero the per-split l accumulators. lbf aliases wv^T (dead after the
    // QKV GEMM above) — round-6 bug was launching this BEFORE the GEMM.
    zero_f32<<<(4 * NH * Tn + 255) / 256, 256, 0, stream>>>(lbf, 4 * NH * Tn);

    // 3) RoPE on q and k in one launch (heads 0..31 of combined buffer)
    rope_bf16<<<(Tn * 32 * 64 + 255) / 256, 256, 0, stream>>>(cqkv, sin_t, cos_t, 32);

    // 4) V^T extraction (overwrites dead wqT region)
    transpose_v<<<dim3(Tn / 32, 512 / 32), 256, 0, stream>>>(cqkv, vtg);

    // 5) MFMA flash attention, unstaged + work-balanced chunks -> bf16 partials
    flash_attn_mfma<<<dim3(40, NH), 256, 0, stream>>>(
        cqkv, vtg, pb01, pb23, lbf);

    // 5b) combine partials -> bf16 abuf
    combine_splits<<<(Tn * Dn / 4 + 255) / 256, 256, 0, stream>>>(pb01, pb23, lbf, abuf);

    // 6) output projection: transpose wo (overwrites vtg region), GEMM
    transpose_cast<<<dim3(Dn / 32, Dn / 32), 256, 0, stream>>>(wo, wt, Dn, Dn, Dn);
    gemm_bf16_mfma<float><<<dim3(Dn / GN, Tn / GM), 256, 0, stream>>>(
        abuf, wt, nullptr, out, Tn, Dn, Dn, Dn);
}

// Round 10
// 512.233 us; speedup vs baseline: 1.1303x; 1.1303x over previous
//
#include <hip/hip_runtime.h>
#include <hip/hip_bf16.h>
#include <math.h>

// Problem constants
#define Tn 2048
#define Dn 3584
#define NH 28
#define KHn 4
#define Hn 128
#define Gn 7            // NH / KHn
#define SCALE 0.08838834764831845f  // 1/sqrt(128)
#define LDC 4608        // combined qkv row stride (q:0..3583, k:3584..4095, v:4096..4607)
#define KOFF 3584
#define VOFF 4096
// flash tiles (block = 128 q-rows, wave owns 2x16 strips)
#define FBQ 128
#define FBS 64
#define MAXT 8          // max KV tiles per block (work-balanced chunks)
// fixed softmax shift: S*scale has std~1.4, |max|~8 << shift; exp(S-12) is
// exactly softmax up to fp rounding (scale cancels in the final divide).
// Also makes split partials ADDITIVE (no max merge) -> free-form chunking.
#define EXP_SHIFT 12.0f

typedef unsigned short u16;
typedef __attribute__((ext_vector_type(8))) short short8;   // 8 bf16 (4 VGPRs)
typedef __attribute__((ext_vector_type(4))) float floatx4;  // MFMA acc

// Work-balanced (qt, s) chunk table: q-tile qt has nst=2qt+2 KV tiles, cut
// into ceil(nst/8) chunks of <=8 tiles. 28 full-8 chunks first (heavy),
// then 12 small gap-fillers. Sum of sizes = 272 tile-units per head.
__device__ __constant__ unsigned char QT_TAB[40] = {
    15,15,15,15, 14,14,14, 13,13,13, 12,12,12, 11,11,11,
    10,10, 9,9, 8,8, 7,7, 6, 5, 4, 3,
    14,10,6,2, 13,9,5,1, 12,8,4,0};
__device__ __constant__ unsigned char S_TAB[40] = {
     0, 1, 2, 3,  0, 1, 2,  0, 1, 2,  0, 1, 2,  0, 1, 2,
     0, 1, 0,1, 0,1, 0,1, 0, 0, 0, 0,
     3, 2,1,0,  3,2,1,0,  3,2,1,0};

// ---------------- bf16 helpers ----------------
__device__ __forceinline__ float bf_lo(unsigned int u) {
    union { unsigned int i; float f; } x; x.i = u << 16; return x.f;
}
__device__ __forceinline__ u16 f2bf(float f) {
    __hip_bfloat16 h = __float2bfloat16(f);
    return *reinterpret_cast<u16*>(&h);
}

// ---------------------------------------------------------------------------
// x fp32 -> bf16 cast (vectorized)
// ---------------------------------------------------------------------------
__global__ void cast_f32_bf16(const float* __restrict__ in, u16* __restrict__ out, int n4)
{
    const int idx = blockIdx.x * blockDim.x + threadIdx.x;
    if (idx >= n4) return;
    const float4 f = ((const float4*)in)[idx];
    ((ushort4*)out)[idx] = make_ushort4(f2bf(f.x), f2bf(f.y), f2bf(f.z), f2bf(f.w));
}

// ---------------------------------------------------------------------------
// zero fp32 buffer (for per-split l accumulators)
// NOTE: lbf aliases the (dead-after-QKV-GEMM) wv^T tail of wt — this kernel
// MUST be launched after the QKV GEMM (round-6 bug: launching it before the
// GEMM zeroed live wv^T weights -> absmax 2.68).
// ---------------------------------------------------------------------------
__global__ void zero_f32(float* __restrict__ p, int n)
{
    const int i = blockIdx.x * blockDim.x + threadIdx.x;
    if (i < n) p[i] = 0.f;
}

// ---------------------------------------------------------------------------
// Transpose + cast: out[c][r] = bf16(in[r][c]); in (R x C) fp32, out stride ldo.
// ---------------------------------------------------------------------------
__global__ __launch_bounds__(256) void transpose_cast(
    const float* __restrict__ in, u16* __restrict__ out, int R, int C, int ldo)
{
    __shared__ float ts[32][33];
    const int tid = threadIdx.x;
    const int c0 = blockIdx.x * 32, r0 = blockIdx.y * 32;
    const int tx = tid & 31, ty = tid >> 5;  // ty 0..7
    #pragma unroll
    for (int i = 0; i < 4; ++i)
        ts[ty + i * 8][tx] = in[(size_t)(r0 + ty + i * 8) * C + c0 + tx];
    __syncthreads();
    #pragma unroll
    for (int i = 0; i < 4; ++i)
        out[(size_t)(c0 + ty + i * 8) * ldo + r0 + tx] = f2bf(ts[tx][ty + i * 8]);
}

// ---------------------------------------------------------------------------
// Transpose V out of combined qkv: vt[D][s] = qkv[s][VOFF + D], D in [0,512)
// ---------------------------------------------------------------------------
__global__ __launch_bounds__(256) void transpose_v(
    const u16* __restrict__ qkv, u16* __restrict__ vt)
{
    __shared__ u16 ts[32][33];
    const int tid = threadIdx.x;
    const int s0 = blockIdx.x * 32, d0 = blockIdx.y * 32;
    const int tx = tid & 31, ty = tid >> 5;
    #pragma unroll
    for (int i = 0; i < 4; ++i)
        ts[ty + i * 8][tx] = qkv[(size_t)(s0 + ty + i * 8) * LDC + VOFF + d0 + tx];
    __syncthreads();
    #pragma unroll
    for (int i = 0; i < 4; ++i)
        vt[(size_t)(d0 + ty + i * 8) * Tn + s0 + tx] = ts[tx][ty + i * 8];
}

// ---------------------------------------------------------------------------
// Concat bias: [q_bias | k_bias | v_bias] -> 4608
// ---------------------------------------------------------------------------
__global__ void concat_bias(const float* __restrict__ qb, const float* __restrict__ kb,
                            const float* __restrict__ vb, float* __restrict__ out)
{
    const int j = blockIdx.x * blockDim.x + threadIdx.x;
    if (j >= 4608) return;
    out[j] = j < 3584 ? qb[j] : (j < 4096 ? kb[j - 3584] : vb[j - 4096]);
}

// ---------------------------------------------------------------------------
// bf16 MFMA GEMM (m97 structure): C[M x N] = A[M x K] * Bt[N x K]^T (+bias)
// + XCD-aware bijective blockIdx swizzle (grids 576/448 are 8-divisible).
// ---------------------------------------------------------------------------
#define GM 128
#define GN 128
#define GK 32

__device__ __forceinline__ void async16(const void* g, void* l) {
    __builtin_amdgcn_global_load_lds(
        (const __attribute__((address_space(1))) unsigned int*)g,
        (__attribute__((address_space(3))) unsigned int*)l, 16, 0, 0);
}

template <typename OUT_T>
__global__ __launch_bounds__(256) void gemm_bf16_mfma(
    const u16* __restrict__ A, const u16* __restrict__ Bt,
    const float* __restrict__ bias, OUT_T* __restrict__ C,
    int M, int N, int K, int ldc)
{
    __shared__ __align__(16) u16 As[GM * GK];   // 8 KB
    __shared__ __align__(16) u16 Bs[GN * GK];   // 8 KB

    const int tid  = threadIdx.x;
    const int lane = tid & 63;
    const int wave = tid >> 6;
    const int wr = wave >> 1, wc = wave & 1;
    const int m16 = lane & 15, quad = lane >> 4;

    // XCD-aware swizzle: 8 XCDs get contiguous block ranges (L2 locality).
    const int nwg = gridDim.x * gridDim.y;      // divisible by 8 for our shapes
    const int bid = blockIdx.y * gridDim.x + blockIdx.x;
    const int cpx = nwg >> 3;
    const int swz = (bid & 7) * cpx + (bid >> 3);
    const int bm = (swz / gridDim.x) * GM;
    const int bn = (swz % gridDim.x) * GN;

    floatx4 acc[4][4];
    #pragma unroll
    for (int i = 0; i < 4; ++i)
        #pragma unroll
        for (int j = 0; j < 4; ++j) acc[i][j] = (floatx4)0.f;

    const int rl   = lane >> 2;
    const int kcol = (lane & 3) * 8;

    for (int k0 = 0; k0 < K; k0 += GK) {
        __syncthreads();
        #pragma unroll
        for (int i = 0; i < 2; ++i) {
            const int c = wave + i * 4;
            const int row = c * 16 + rl;
            async16(A  + (size_t)(bm + row) * K + k0 + kcol, &As[c * 512]);
            async16(Bt + (size_t)(bn + row) * K + k0 + kcol, &Bs[c * 512]);
        }
        __builtin_amdgcn_s_waitcnt(0);
        __syncthreads();

        short8 af[4], bfr[4];
        #pragma unroll
        for (int i = 0; i < 4; ++i)
            af[i] = *(const short8*)&As[(wr * 64 + i * 16 + m16) * GK + quad * 8];
        #pragma unroll
        for (int j = 0; j < 4; ++j)
            bfr[j] = *(const short8*)&Bs[(wc * 64 + j * 16 + m16) * GK + quad * 8];
        #pragma unroll
        for (int i = 0; i < 4; ++i)
            #pragma unroll
            for (int j = 0; j < 4; ++j)
                acc[i][j] = __builtin_amdgcn_mfma_f32_16x16x32_bf16(
                    af[i], bfr[j], acc[i][j], 0, 0, 0);
    }

    #pragma unroll
    for (int j = 0; j < 4; ++j) {
        const int col = bn + wc * 64 + j * 16 + m16;
        const float bv = bias ? bias[col] : 0.f;
        #pragma unroll
        for (int i = 0; i < 4; ++i) {
            const int rbase = bm + wr * 64 + i * 16 + quad * 4;
            #pragma unroll
            for (int r = 0; r < 4; ++r) {
                const float v = acc[i][j][r] + bv;
                if constexpr (sizeof(OUT_T) == 2)
                    C[(size_t)(rbase + r) * ldc + col] = (OUT_T)f2bf(v);
                else
                    C[(size_t)(rbase + r) * ldc + col] = v;
            }
        }
    }
}

// ---------------------------------------------------------------------------
// RoPE in place on bf16 strided buffer. heads=32 covers q (0..27) + k (28..31).
// ---------------------------------------------------------------------------
__global__ void rope_bf16(u16* __restrict__ base,
                          const float* __restrict__ sin_t,
                          const float* __restrict__ cos_t,
                          int heads)
{
    const int idx = blockIdx.x * blockDim.x + threadIdx.x;
    const int n_elem = Tn * heads * 64;
    if (idx >= n_elem) return;
    const int i = idx & 63;
    const int h = (idx >> 6) % heads;
    const int t = idx / (64 * heads);
    const float s = sin_t[t * 64 + i];
    const float c = cos_t[t * 64 + i];
    u16* p = base + (size_t)t * LDC + h * Hn;
    const float x1 = bf_lo((unsigned int)p[i]);
    const float x2 = bf_lo((unsigned int)p[i + 64]);
    p[i]      = f2bf(x1 * c - x2 * s);
    p[i + 64] = f2bf(x2 * c + x1 * s);
}

// ---------------------------------------------------------------------------
// MFMA flash attention: r7's LDS-staged compute path (fast: 138us) with
// TRANSIENT staging registers (r9's lesson: cross-iteration VGPR prefetch
// caused ~200MB phantom scratch writes; r9 without it had WRITE_SIZE ==
// data exactly). Per tile: load 8x uint4 at iteration top, immediately
// ds_write, no value lives across the compute section. Work-balanced
// <=8-tile chunks + fixed-shift softmax + clean full-line O epilogue
// re-staged through dead Ps (r9-proven).
// ---------------------------------------------------------------------------
__global__ __launch_bounds__(256, 2) void flash_attn_mfma(
    const u16* __restrict__ qkv, const u16* __restrict__ vt,
    u16* __restrict__ pb01, u16* __restrict__ pb23,
    float* __restrict__ lb)
{
    const int qt = (int)QT_TAB[blockIdx.x];
    const int s  = (int)S_TAB[blockIdx.x];
    const int n  = blockIdx.y;
    const int kh = n / Gn;
    const int tid  = threadIdx.x;
    const int lane = tid & 63;
    const int w    = tid >> 6;
    const int m16  = lane & 15;
    const int quad = lane >> 4;

    __shared__ __align__(16) u16 smem[64 * 136 + 128 * 72 + 128 * 72];  // 54272 B
    u16* Ks = smem;                    // [64 s][136]
    u16* Vs = smem + 64 * 136;         // [128 d][72]
    u16* Ps = Vs + 128 * 72;           // [128 m][72]  wave-private rows

    // Q fragments (A-operand), rows w*32 + p*16 + m16, loaded once
    short8 qf[2][4];
    #pragma unroll
    for (int p = 0; p < 2; ++p) {
        const int qrow = qt * FBQ + w * 32 + p * 16 + m16;
        const u16* qp = qkv + (size_t)qrow * LDC + n * Hn;
        #pragma unroll
        for (int kc = 0; kc < 4; ++kc)
            qf[p][kc] = *(const short8*)(qp + kc * 32 + quad * 8);
    }

    floatx4 oacc[2][8];
    #pragma unroll
    for (int p = 0; p < 2; ++p)
        #pragma unroll
        for (int jn = 0; jn < 8; ++jn) oacc[p][jn] = (floatx4)0.f;
    float lrow[2][4];
    #pragma unroll
    for (int p = 0; p < 2; ++p)
        #pragma unroll
        for (int r = 0; r < 4; ++r) lrow[p][r] = 0.f;

    const int krow = tid >> 2, kseg = tid & 3;
    const int vrow = tid >> 1, vseg = tid & 1;
    const int nst = 2 * qt + 2;
    const int st0 = s * MAXT;
    const int st1 = (st0 + MAXT < nst) ? st0 + MAXT : nst;

    // per-thread staging source bases (advance by st*FBS each tile)
    const u16* kbase = qkv + (size_t)krow * LDC + KOFF + kh * Hn + kseg * 32;
    const u16* vbase = vt + (size_t)(kh * Hn + vrow) * Tn + vseg * 32;

    for (int st = st0; st < st1; ++st) {
        __syncthreads();   // previous iteration's LDS reads done
        {
            // TRANSIENT staging: load -> write, nothing live past this block
            const u16* kp = kbase + (size_t)(st * FBS) * LDC;
            const u16* vp = vbase + st * FBS;
            uint4 kv[4], vv[4];
            #pragma unroll
            for (int i = 0; i < 4; ++i) kv[i] = *(const uint4*)(kp + i * 8);
            #pragma unroll
            for (int i = 0; i < 4; ++i) vv[i] = *(const uint4*)(vp + i * 8);
            #pragma unroll
            for (int i = 0; i < 4; ++i)
                *(uint4*)&Ks[krow * 136 + kseg * 32 + i * 8] = kv[i];
            #pragma unroll
            for (int i = 0; i < 4; ++i)
                *(uint4*)&Vs[vrow * 72 + vseg * 32 + i * 8] = vv[i];
        }
        __syncthreads();

        // wave-uniform skip of fully-masked wave-tiles
        const bool active = (st * FBS) <= (qt * FBQ + w * 32 + 31);
        if (active) {
            // ---------------- QK^T ----------------
            floatx4 sacc[2][4];
            #pragma unroll
            for (int p = 0; p < 2; ++p)
                #pragma unroll
                for (int j = 0; j < 4; ++j) sacc[p][j] = (floatx4)0.f;
            #pragma unroll
            for (int j = 0; j < 4; ++j) {
                #pragma unroll
                for (int kc = 0; kc < 4; ++kc) {
                    const short8 bfv = *(const short8*)&Ks[(j * 16 + m16) * 136 + kc * 32 + quad * 8];
                    sacc[0][j] = __builtin_amdgcn_mfma_f32_16x16x32_bf16(qf[0][kc], bfv, sacc[0][j], 0, 0, 0);
                    sacc[1][j] = __builtin_amdgcn_mfma_f32_16x16x32_bf16(qf[1][kc], bfv, sacc[1][j], 0, 0, 0);
                }
            }

            // ---- fixed-shift softmax: P = exp(S*scale - 12), no max chain ----
            const bool diag = (st >= 2 * qt);
            #pragma unroll
            for (int p = 0; p < 2; ++p) {
                #pragma unroll
                for (int r = 0; r < 4; ++r) {
                    const int prow = w * 32 + p * 16 + quad * 4 + r;
                    const int row  = qt * FBQ + prow;
                    float ls = 0.f;
                    #pragma unroll
                    for (int j = 0; j < 4; ++j) {
                        float sv = sacc[p][j][r] * SCALE - EXP_SHIFT;
                        if (diag && (st * FBS + j * 16 + m16 > row)) sv = -1.0e30f;
                        const float e = __expf(sv);
                        ls += e;
                        Ps[prow * 72 + j * 16 + m16] = f2bf(e);
                    }
                    lrow[p][r] += ls;   // lane-partial, no rescale needed
                }
            }

            // ---------------- PV ----------------
            #pragma unroll
            for (int kc2 = 0; kc2 < 2; ++kc2) {
                const short8 af0 = *(const short8*)&Ps[(w * 32 + m16) * 72 + kc2 * 32 + quad * 8];
                const short8 af1 = *(const short8*)&Ps[(w * 32 + 16 + m16) * 72 + kc2 * 32 + quad * 8];
                #pragma unroll
                for (int jn = 0; jn < 8; ++jn) {
                    const short8 bfv = *(const short8*)&Vs[(jn * 16 + m16) * 72 + kc2 * 32 + quad * 8];
                    oacc[0][jn] = __builtin_amdgcn_mfma_f32_16x16x32_bf16(af0, bfv, oacc[0][jn], 0, 0, 0);
                    oacc[1][jn] = __builtin_amdgcn_mfma_f32_16x16x32_bf16(af1, bfv, oacc[1][jn], 0, 0, 0);
                }
            }
        }
    }

    // ---- epilogue: butterfly-reduce l, local-normalize ----
    float lsum[2][4], invl[2][4];
    #pragma unroll
    for (int p = 0; p < 2; ++p)
        #pragma unroll
        for (int r = 0; r < 4; ++r) {
            float l = lrow[p][r];
            l += __shfl_xor(l, 1); l += __shfl_xor(l, 2);
            l += __shfl_xor(l, 4); l += __shfl_xor(l, 8);
            lsum[p][r] = l;
            invl[p][r] = (l > 0.f) ? 1.0f / l : 0.f;
        }

    if (m16 == 0) {
        #pragma unroll
        for (int p = 0; p < 2; ++p)
            #pragma unroll
            for (int r = 0; r < 4; ++r) {
                const int row = qt * FBQ + w * 32 + p * 16 + quad * 4 + r;
                lb[((size_t)s * NH + n) * Tn + row] = lsum[p][r];
            }
    }

    // ---- O store: re-stage through dead Ps (wave-private rows, no barrier
    // needed: PV reads only this wave's Ps rows) -> full 64B-line stores.
    u16* po = (s < 2) ? pb01 + (size_t)s * Tn * Dn
                      : pb23 + (size_t)(s - 2) * Tn * Dn;
    const int orow_l = w * 32 + (lane >> 1);       // this lane's readback row
    const int seg    = lane & 1;
    __syncthreads();   // all waves finished PV reads of Ps before overwrite
    #pragma unroll
    for (int h = 0; h < 2; ++h) {                  // column halves 0-63, 64-127
        // stage: wave's 32 rows x 64 cols into Ps[row][0..63]
        #pragma unroll
        for (int p = 0; p < 2; ++p)
            #pragma unroll
            for (int r = 0; r < 4; ++r) {
                const int mrw = w * 32 + p * 16 + quad * 4 + r;
                #pragma unroll
                for (int j4 = 0; j4 < 4; ++j4)
                    Ps[mrw * 72 + j4 * 16 + m16] =
                        f2bf(oacc[p][h * 4 + j4][r] * invl[p][r]);
            }
        // readback: 2 lanes/row x 64B contiguous (full lines)
        u16* orow = po + (size_t)(qt * FBQ + orow_l) * Dn + n * Hn + h * 64 + seg * 32;
        #pragma unroll
        for (int i = 0; i < 4; ++i) {
            const uint4 d = *(const uint4*)&Ps[orow_l * 72 + seg * 32 + i * 8];
            *(uint4*)(orow + i * 8) = d;
        }
    }
}

// ---------------------------------------------------------------------------
// Combine up to 4 normalized bf16 partials: out = sum(l_i*o_i)/sum(l_i).
// Slots with l==0 (unused splits for this qt) are skipped.
// ---------------------------------------------------------------------------
__global__ __launch_bounds__(256) void combine_splits(
    const u16* __restrict__ pb01, const u16* __restrict__ pb23,
    const float* __restrict__ lb, u16* __restrict__ ob)
{
    const int idx = blockIdx.x * blockDim.x + threadIdx.x;
    const int n4  = Tn * Dn / 4;
    if (idx >= n4) return;
    const int c4  = idx % (Dn / 4);
    const int row = idx / (Dn / 4);
    const int n   = (c4 * 4) >> 7;   // /Hn

    float den = 0.f, ax = 0.f, ay = 0.f, az = 0.f, aw = 0.f;
    #pragma unroll
    for (int s = 0; s < 4; ++s) {
        const float l = lb[((size_t)s * NH + n) * Tn + row];
        if (l > 0.f) {
            const u16* p = (s < 2) ? pb01 + (size_t)s * Tn * Dn
                                   : pb23 + (size_t)(s - 2) * Tn * Dn;
            const ushort4 v = ((const ushort4*)p)[idx];
            den += l;
            ax += l * bf_lo((unsigned int)v.x);
            ay += l * bf_lo((unsigned int)v.y);
            az += l * bf_lo((unsigned int)v.z);
            aw += l * bf_lo((unsigned int)v.w);
        }
    }
    const float inv = 1.0f / den;   // s=0 always populated
    ushort4 o;
    o.x = f2bf(ax * inv);
    o.y = f2bf(ay * inv);
    o.z = f2bf(az * inv);
    o.w = f2bf(aw * inv);
    ((ushort4*)ob)[idx] = o;
}

// ---------------------------------------------------------------------------
// Launch
// ---------------------------------------------------------------------------
extern "C" void kernel_launch(void* const* d_in, const int* in_sizes, int n_in,
                              void* d_out, int out_size, void* d_ws, size_t ws_size,
                              hipStream_t stream)
{
    const float* x      = (const float*)d_in[0];
    const float* sin_t  = (const float*)d_in[2];
    const float* cos_t  = (const float*)d_in[3];
    const float* wq     = (const float*)d_in[4];
    const float* wk     = (const float*)d_in[5];
    const float* wv     = (const float*)d_in[6];
    const float* wo     = (const float*)d_in[7];
    const float* q_bias = (const float*)d_in[8];
    const float* k_bias = (const float*)d_in[9];
    const float* v_bias = (const float*)d_in[10];
    float* out = (float*)d_out;

    char* ws = (char*)d_ws;
    u16*  cqkv = (u16*)ws;                                  // 2048*4608 bf16 = 18,874,368
    u16*  abuf = (u16*)(ws + 18874368);                     // 2048*3584 bf16 = 14,680,064
    u16*  wt   = (u16*)(ws + 18874368 + 14680064);          // 4608*3584 bf16 (reused); @33,554,432
    float* bqkv = (float*)(ws + 66584576);                  // 4608 fp32
    u16*  vtg  = wt;                // V^T [512][2048] aliases wt head (2,097,152 B)
    // flash partials (live: flash -> combine only), bf16 normalized:
    // slots 0,1 -> d_out (xb dead); slots 2,3 -> dead wt region past vtg.
    u16*  pb01 = (u16*)d_out;                      // 2 x 14,680,064 = 29,360,128 (exact fit)
    u16*  pb23 = (u16*)(ws + 35651584);            // 2 x 14,680,064, ends 65,011,712
    float* lbf = (float*)(ws + 65011712);          // 4*28*2048*4 = 917,504, ends 65,929,216
    u16*  xb   = (u16*)d_out;   // x-bf16 scratch in d_out (dead before flash)

    // 1) casts / transposes / bias concat
    cast_f32_bf16<<<(Tn * Dn / 4 + 255) / 256, 256, 0, stream>>>(x, xb, Tn * Dn / 4);
    transpose_cast<<<dim3(Dn / 32, Dn / 32), 256, 0, stream>>>(wq, wt, Dn, Dn, Dn);
    transpose_cast<<<dim3(512 / 32, Dn / 32), 256, 0, stream>>>(wk, wt + (size_t)KOFF * Dn, Dn, 512, Dn);
    transpose_cast<<<dim3(512 / 32, Dn / 32), 256, 0, stream>>>(wv, wt + (size_t)VOFF * Dn, Dn, 512, Dn);
    concat_bias<<<18, 256, 0, stream>>>(q_bias, k_bias, v_bias, bqkv);

    // 2) fused QKV projection (bf16 MFMA)
    gemm_bf16_mfma<u16><<<dim3(LDC / GN, Tn / GM), 256, 0, stream>>>(
        xb, wt, bqkv, cqkv, Tn, LDC, Dn, LDC);

    // 2b) zero the per-split l accumulators. lbf aliases wv^T (dead after the
    // QKV GEMM above) — round-6 bug was launching this BEFORE the GEMM.
    zero_f32<<<(4 * NH * Tn + 255) / 256, 256, 0, stream>>>(lbf, 4 * NH * Tn);

    // 3) RoPE on q and k in one launch (heads 0..31 of combined buffer)
    rope_bf16<<<(Tn * 32 * 64 + 255) / 256, 256, 0, stream>>>(cqkv, sin_t, cos_t, 32);

    // 4) V^T extraction (overwrites dead wqT region)
    transpose_v<<<dim3(Tn / 32, 512 / 32), 256, 0, stream>>>(cqkv, vtg);

    // 5) MFMA flash attention, staged w/ transient regs, work-balanced chunks
    flash_attn_mfma<<<dim3(40, NH), 256, 0, stream>>>(
        cqkv, vtg, pb01, pb23, lbf);

    // 5b) combine partials -> bf16 abuf
    combine_splits<<<(Tn * Dn / 4 + 255) / 256, 256, 0, stream>>>(pb01, pb23, lbf, abuf);

    // 6) output projection: transpose wo (overwrites vtg region), GEMM
    transpose_cast<<<dim3(Dn / 32, Dn / 32), 256, 0, stream>>>(wo, wt, Dn, Dn, Dn);
    gemm_bf16_mfma<float><<<dim3(Dn / GN, Tn / GM), 256, 0, stream>>>(
        abuf, wt, nullptr, out, Tn, Dn, Dn, Dn);
}